// Round 12
// baseline (525.625 us; speedup 1.0000x reference)
//
#include <hip/hip_runtime.h>

// Problem constants (fixed by the reference)
constexpr int CH    = 384;    // channels
constexpr int NPIX  = 1024;   // H*W = 32*32
constexpr int NHEAD = 12;
constexpr int DH    = 32;     // head dim
constexpr int NB    = 16;     // batch
constexpr float SCALE = 0.17677669529663689f;  // 32^-0.5
constexpr float LOG2E = 1.4426950408889634f;

typedef __attribute__((ext_vector_type(8))) short bf16x8;  // 8 bf16 (4 VGPRs)
typedef __attribute__((ext_vector_type(4))) float f32x4;   // MFMA C/D frag

// Fragment-major ("swizzled") operand layout for the LDS-free GEMMs:
// a K-major matrix [R][384] is stored as [R/16][12] blocks of 512 bf16;
// lane (quad*16+cc) holds row cc, k = quad*8..+7 of the 32-wide k-chunk, at
// offset lane*8.  Fragment load = base + lane*8 -> 1 KB coalesced per wave.
// elem (r, ch): off = ((r>>4)*12 + (ch>>5))*512 + (((ch>>3)&3)*16 + (r&15))*8 + (ch&7)

// pack two fp32 -> two bf16, round-half-up (3 VALU)
__device__ __forceinline__ unsigned pk2(float a, float b) {
  return __builtin_amdgcn_perm(__float_as_uint(b) + 0x8000u,
                               __float_as_uint(a) + 0x8000u, 0x07060302u);
}
// pack two fp32 -> two bf16, TRUNCATE (1 VALU) — P only; bias cancels in P/l.
__device__ __forceinline__ unsigned pk2t(float a, float b) {
  return __builtin_amdgcn_perm(__float_as_uint(b), __float_as_uint(a), 0x07060302u);
}

// 2^x on the VALU (v_exp_f32 computes 2^x natively)
#if __has_builtin(__builtin_amdgcn_exp2f)
#define EXP2F(x) __builtin_amdgcn_exp2f(x)
#else
#define EXP2F(x) exp2f(x)
#endif

// ---------------------------------------------------------------------------
// Fused prep: blocks [0,1536) transpose x [b][c][n] fp32 -> xt swizzled bf16;
// blocks [1536,2112) convert weights to swizzled bf16 (Q rows pre-scaled by
// SCALE*log2e: base-2 logits).
// ---------------------------------------------------------------------------
__global__ __launch_bounds__(256) void prep_fused(
    const float* __restrict__ x, const float* __restrict__ qw,
    const float* __restrict__ pw, unsigned short* __restrict__ xts,
    unsigned short* __restrict__ wqs, unsigned short* __restrict__ pws) {
  const int bx = blockIdx.x;
  const int tid = threadIdx.x;
  if (bx < 1536) {
    __shared__ float T[64][65];
    const int b = bx / 96, rem = bx - b * 96;
    const int c0 = (rem >> 4) * 64, n0 = (rem & 15) * 64;
    const float* xb = x + ((size_t)b * CH + c0) * NPIX + n0;
    const int rn = (tid & 15) * 4, rc = tid >> 4;
#pragma unroll
    for (int i = 0; i < 4; i++) {
      float4 v = *(const float4*)(xb + (size_t)(rc + i * 16) * NPIX + rn);
      T[rc + i * 16][rn + 0] = v.x;
      T[rc + i * 16][rn + 1] = v.y;
      T[rc + i * 16][rn + 2] = v.z;
      T[rc + i * 16][rn + 3] = v.w;
    }
    __syncthreads();
    const int wc = (tid & 15) * 4;  // channel offset within the 64-wide c tile
    const int ch = c0 + wc;         // 4 consecutive channels
    const int kc = ch >> 5, qd = (ch >> 3) & 3, j = ch & 7;
#pragma unroll
    for (int i = 0; i < 4; i++) {
      const int nl = (tid >> 4) + i * 16;       // local pixel row
      const int ng = n0 + nl;
      uint2 p = {pk2(T[wc][nl], T[wc + 1][nl]), pk2(T[wc + 2][nl], T[wc + 3][nl])};
      size_t off = (((size_t)b * 64 + (ng >> 4)) * 12 + kc) * 512 +
                   (qd * 16 + (ng & 15)) * 8 + j;
      *(uint2*)(xts + off) = p;
    }
  } else {
    const int idx = (bx - 1536) * 256 + tid;
    if (idx < 110592) {
      float4 v = ((const float4*)qw)[idx];
      const int o  = (idx * 4) / CH;  // 4 | 384: never crosses a row
      const int ch = (idx * 4) - o * CH;
      const float sc = (o < CH) ? SCALE * LOG2E : 1.0f;
      size_t off = (((size_t)(o >> 4)) * 12 + (ch >> 5)) * 512 +
                   (((ch >> 3) & 3) * 16 + (o & 15)) * 8 + (ch & 7);
      *(uint2*)(wqs + off) =
          (uint2){pk2(v.x * sc, v.y * sc), pk2(v.z * sc, v.w * sc)};
    } else {
      const int jdx = idx - 110592;
      float4 v = ((const float4*)pw)[jdx];
      const int o  = (jdx * 4) / CH;
      const int ch = (jdx * 4) - o * CH;
      size_t off = (((size_t)(o >> 4)) * 12 + (ch >> 5)) * 512 +
                   (((ch >> 3) & 3) * 16 + (o & 15)) * 8 + (ch & 7);
      *(uint2*)(pws + off) = (uint2){pk2(v.x, v.y), pk2(v.z, v.w)};
    }
  }
}

// ---------------------------------------------------------------------------
// QKV GEMM (R11 swizzled LDS-free; launch_bounds 4 waves/SIMD).
// ---------------------------------------------------------------------------
__global__ __launch_bounds__(256, 4) void qkv_mfma(
    const unsigned short* __restrict__ xts, const unsigned short* __restrict__ wqs,
    unsigned short* __restrict__ qb, unsigned short* __restrict__ kb,
    unsigned short* __restrict__ vtb) {
  const int bx = blockIdx.x;          // b = bx>>3, ntile = bx&7
  const int b  = bx >> 3;
  const int n0 = (bx & 7) * 128;
  const int m0 = blockIdx.y * 128;    // 0..8
  const int qkv_t = blockIdx.y / 3;   // 0=Q, 1=K, 2=V
  const int tid = threadIdx.x, wave = tid >> 6, lane = tid & 63;
  const int wm = (wave >> 1) * 64, wn = (wave & 1) * 64;
  const int cc = lane & 15, quad = lane >> 4;

  const unsigned short* abase =
      wqs + ((size_t)((m0 + wm) >> 4) * 12) * 512 + lane * 8;
  const unsigned short* bbase =
      xts + (((size_t)b * 64 + ((n0 + wn) >> 4)) * 12) * 512 + lane * 8;

  f32x4 acc[4][4];
#pragma unroll
  for (int i = 0; i < 4; i++)
#pragma unroll
    for (int j = 0; j < 4; j++) acc[i][j] = (f32x4){0.f, 0.f, 0.f, 0.f};

  bf16x8 af[4], bfr[4];
#pragma unroll
  for (int t = 0; t < 4; t++) af[t] = *(const bf16x8*)(abase + (size_t)(t * 12) * 512);
#pragma unroll
  for (int t = 0; t < 4; t++) bfr[t] = *(const bf16x8*)(bbase + (size_t)(t * 12) * 512);

#pragma unroll 2
  for (int kc = 0; kc < 12; kc++) {
    const int k2 = (kc + 1 < 12) ? kc + 1 : 0;  // wrap: redundant, in-bounds
    bf16x8 naf[4], nbf[4];
#pragma unroll
    for (int t = 0; t < 4; t++)
      naf[t] = *(const bf16x8*)(abase + (size_t)(t * 12 + k2) * 512);
#pragma unroll
    for (int t = 0; t < 4; t++)
      nbf[t] = *(const bf16x8*)(bbase + (size_t)(t * 12 + k2) * 512);

    if (qkv_t < 2) {
#pragma unroll
      for (int i = 0; i < 4; i++)
#pragma unroll
        for (int j = 0; j < 4; j++)
          acc[i][j] = __builtin_amdgcn_mfma_f32_16x16x32_bf16(af[i], bfr[j], acc[i][j], 0, 0, 0);
    } else {  // V: swap -> C rows = pixels, cols = weight-o
#pragma unroll
      for (int i = 0; i < 4; i++)
#pragma unroll
        for (int j = 0; j < 4; j++)
          acc[i][j] = __builtin_amdgcn_mfma_f32_16x16x32_bf16(bfr[i], af[j], acc[i][j], 0, 0, 0);
    }
#pragma unroll
    for (int t = 0; t < 4; t++) { af[t] = naf[t]; bfr[t] = nbf[t]; }
  }

  const int obase = m0 - qkv_t * CH;  // 0/128/256 within the Q/K/V segment
  if (qkv_t < 2) {
    unsigned short* dst0 = (qkv_t == 0) ? qb : kb;
#pragma unroll
    for (int mt = 0; mt < 4; mt++) {
      const int o = obase + wm + mt * 16 + quad * 4;  // [0,384)
      const int h = o >> 5, d0 = o & 31;
      unsigned short* drow = dst0 + ((size_t)(b * NHEAD + h) * NPIX) * DH + d0;
#pragma unroll
      for (int nt = 0; nt < 4; nt++) {
        const int n = n0 + wn + nt * 16 + cc;
        uint2 p = {pk2(acc[mt][nt][0], acc[mt][nt][1]),
                   pk2(acc[mt][nt][2], acc[mt][nt][3])};
        *(uint2*)(drow + (size_t)n * DH) = p;
      }
    }
  } else {
#pragma unroll
    for (int i = 0; i < 4; i++) {
      const int nbase = n0 + wn + i * 16 + quad * 4;
#pragma unroll
      for (int j = 0; j < 4; j++) {
        const int od = obase + wm + j * 16 + cc;
        const int h = od >> 5, dd = od & 31;
        unsigned short* vrow = vtb + ((size_t)(b * NHEAD + h) * DH + dd) * NPIX;
        *(uint2*)(vrow + nbase) = (uint2){pk2(acc[i][j][0], acc[i][j][1]),
                                          pk2(acc[i][j][2], acc[i][j][3])};
      }
    }
  }
}

// ---------------------------------------------------------------------------
// MFMA attention v11: R9 VALU-diet loop + 2-way split-K wave pairs.
// Block = 4 waves = 2 q-subtiles x 2 key-halves; each wave 64 queries
// (4 groups, full amortization) over 512 keys (16 iters).  Grid (192, 8) =
// 1536 blocks = 6 blocks/CU = 6 waves/SIMD (2x R9's residency).
// Unnormalized partials (O, l) add exactly; combined through LDS (reuses
// Pbuf, which is exactly the right size).  Denominator on the matrix pipe
// (ones-MFMA over the same truncated P the PV consumes); truncate-pack;
// skewed pipeline; XCD-pinned grid (192 % 8 == 0).
// Output written in proj's fragment-major layout.
// ---------------------------------------------------------------------------
__global__ __launch_bounds__(256, 6) void attn_mfma(
    const unsigned short* __restrict__ qb, const unsigned short* __restrict__ kb,
    const unsigned short* __restrict__ vtb, unsigned short* __restrict__ ao) {
  constexpr int PSTR = 36;  // 72 B rows: 18c mod 32 hits all 16 even residues
  // 18432 B; doubles as the split-K combine buffer (1152 float4)
  __shared__ __align__(16) unsigned short Pbuf[4][4][16][PSTR];

  const int bh   = blockIdx.x;  // 0..191  (x-major -> XCD = bh % 8)
  const int b    = bh / NHEAD;
  const int h    = bh - b * NHEAD;
  const int tid  = threadIdx.x;
  const int wave = tid >> 6;
  const int half = wave & 1;    // key half
  const int pairq = wave >> 1;  // q-subtile within block
  const int lane = tid & 63;
  const int c    = lane & 15;
  const int Q0   = lane >> 4;
  const int q0   = blockIdx.y * 128 + pairq * 64;

  bf16x8 Bq[4];
#pragma unroll
  for (int g = 0; g < 4; g++)
    Bq[g] = *(const bf16x8*)(qb + ((size_t)bh * NPIX + q0 + 16 * g + c) * DH + Q0 * 8);

  const unsigned short* kh  = kb + ((size_t)bh * NPIX + half * 512) * DH;
  const unsigned short* v0h = vtb + ((size_t)bh * DH + c) * NPIX + half * 512;
  const unsigned short* v1h = vtb + ((size_t)bh * DH + c + 16) * NPIX + half * 512;

  const f32x4 zero = {0.f, 0.f, 0.f, 0.f};
  const bf16x8 zero8 = {0, 0, 0, 0, 0, 0, 0, 0};
  const short ONE = (short)0x3F80;  // bf16 1.0
  const bf16x8 ones = {ONE, ONE, ONE, ONE, ONE, ONE, ONE, ONE};

  f32x4 o0[4], o1[4], ls[4];
#pragma unroll
  for (int g = 0; g < 4; g++) { o0[g] = zero; o1[g] = zero; ls[g] = zero; }

  unsigned short* prow[4];
#pragma unroll
  for (int g = 0; g < 4; g++) prow[g] = &Pbuf[wave][g][c][0];

  bf16x8 Ka0 = *(const bf16x8*)(kh + (size_t)c * DH + Q0 * 8);  // K(0)
  bf16x8 Ka1 = *(const bf16x8*)(kh + (size_t)(16 + c) * DH + Q0 * 8);
  bf16x8 Vr0 = zero8, Vr1 = zero8;              // V(t-1); PV(-1) adds 0
  bf16x8 Bp[4] = {zero8, zero8, zero8, zero8};  // P(t-1)

#pragma unroll 2
  for (int kt = 0; kt < 512; kt += 32) {
    const int kt2 = (kt + 32) & 511;  // wrap on last iter (redundant, in-bounds)
    bf16x8 nKa0 = *(const bf16x8*)(kh + (size_t)(kt2 + c) * DH + Q0 * 8);
    bf16x8 nKa1 = *(const bf16x8*)(kh + (size_t)(kt2 + 16 + c) * DH + Q0 * 8);
    bf16x8 nVa0 = *(const bf16x8*)(v0h + kt + Q0 * 8);
    bf16x8 nVa1 = *(const bf16x8*)(v1h + kt + Q0 * 8);

    // S(t) = K(t) . Q^T  (8 MFMA)
    f32x4 s0[4], s1[4];
#pragma unroll
    for (int g = 0; g < 4; g++) {
      s0[g] = __builtin_amdgcn_mfma_f32_16x16x32_bf16(Ka0, Bq[g], zero, 0, 0, 0);
      s1[g] = __builtin_amdgcn_mfma_f32_16x16x32_bf16(Ka1, Bq[g], zero, 0, 0, 0);
    }

    // PV(t-1) + denominator(t-1): 12 MFMA, all operands in registers
#pragma unroll
    for (int g = 0; g < 4; g++) {
      o0[g] = __builtin_amdgcn_mfma_f32_16x16x32_bf16(Vr0, Bp[g], o0[g], 0, 0, 0);
      o1[g] = __builtin_amdgcn_mfma_f32_16x16x32_bf16(Vr1, Bp[g], o1[g], 0, 0, 0);
      ls[g] = __builtin_amdgcn_mfma_f32_16x16x32_bf16(ones, Bp[g], ls[g], 0, 0, 0);
    }

    // p = 2^s, truncate-pack, LDS round-trip for P(t)
#pragma unroll
    for (int g = 0; g < 4; g++) {
      float p0[4], p1[4];
#pragma unroll
      for (int r = 0; r < 4; r++) p0[r] = EXP2F(s0[g][r]);
#pragma unroll
      for (int r = 0; r < 4; r++) p1[r] = EXP2F(s1[g][r]);
      *(uint2*)(prow[g] + 4 * Q0)      = (uint2){pk2t(p0[0], p0[1]), pk2t(p0[2], p0[3])};
      *(uint2*)(prow[g] + 16 + 4 * Q0) = (uint2){pk2t(p1[0], p1[1]), pk2t(p1[2], p1[3])};
    }
#pragma unroll
    for (int g = 0; g < 4; g++) Bp[g] = *(const bf16x8*)(prow[g] + 8 * Q0);

    Ka0 = nKa0; Ka1 = nKa1; Vr0 = nVa0; Vr1 = nVa1;
  }

  // drain: PV(last) + denominator(last)
#pragma unroll
  for (int g = 0; g < 4; g++) {
    o0[g] = __builtin_amdgcn_mfma_f32_16x16x32_bf16(Vr0, Bp[g], o0[g], 0, 0, 0);
    o1[g] = __builtin_amdgcn_mfma_f32_16x16x32_bf16(Vr1, Bp[g], o1[g], 0, 0, 0);
    ls[g] = __builtin_amdgcn_mfma_f32_16x16x32_bf16(ones, Bp[g], ls[g], 0, 0, 0);
  }

  // ---- split-K combine (exact: unnormalized partials add) ----
  float4* cb = (float4*)&Pbuf[0][0][0][0];   // 1152 float4
  float4* ob = cb + (size_t)pairq * 8 * 64;  // 8 slots per q-subtile
  __syncthreads();                           // all Pbuf P-reads done
  if (half) {
#pragma unroll
    for (int g = 0; g < 4; g++) {
      ob[(g * 2 + 0) * 64 + lane] = (float4){o0[g][0], o0[g][1], o0[g][2], o0[g][3]};
      ob[(g * 2 + 1) * 64 + lane] = (float4){o1[g][0], o1[g][1], o1[g][2], o1[g][3]};
    }
    cb[1024 + pairq * 64 + lane] = (float4){ls[0][0], ls[1][0], ls[2][0], ls[3][0]};
  }
  __syncthreads();
  if (!half) {
    const float4 lo = cb[1024 + pairq * 64 + lane];
    const float lt[4] = {ls[0][0] + lo.x, ls[1][0] + lo.y,
                         ls[2][0] + lo.z, ls[3][0] + lo.w};
#pragma unroll
    for (int g = 0; g < 4; g++) {
      const float4 a0 = ob[(g * 2 + 0) * 64 + lane];
      const float4 a1 = ob[(g * 2 + 1) * 64 + lane];
      const float inv = 1.0f / lt[g];
      // proj fragment-major store: row-block (q0>>4)+g, k-chunk h, row c
      unsigned short* op = ao +
          (((size_t)b * 64 + (q0 >> 4) + g) * 12 + h) * 512 + c * 8 + 4 * (Q0 & 1);
      *(uint2*)(op + (Q0 >> 1) * 128) =
          (uint2){pk2((o0[g][0] + a0.x) * inv, (o0[g][1] + a0.y) * inv),
                  pk2((o0[g][2] + a0.z) * inv, (o0[g][3] + a0.w) * inv)};
      *(uint2*)(op + (2 + (Q0 >> 1)) * 128) =
          (uint2){pk2((o1[g][0] + a1.x) * inv, (o1[g][1] + a1.y) * inv),
                  pk2((o1[g][2] + a1.z) * inv, (o1[g][3] + a1.w) * inv)};
    }
  }
}

// ---------------------------------------------------------------------------
// Output projection v4: LDS-free swizzled, 128m x 64n tiles.
// Grid (256, 3) = 768 blocks = 3/CU (was 384 = 1.5/CU: half the CUs idled).
// Same-x m-tiles land on the same XCD (ids differ by 256 == 0 mod 8).
// ---------------------------------------------------------------------------
__global__ __launch_bounds__(256, 4) void proj_mfma(
    const unsigned short* __restrict__ aos, const unsigned short* __restrict__ pws,
    const float* __restrict__ bias, float* __restrict__ out) {
  const int bx = blockIdx.x;          // 0..255: b = bx>>4, ntile = bx&15
  const int b  = bx >> 4;
  const int n0 = (bx & 15) * 64;
  const int m0 = blockIdx.y * 128;
  const int tid = threadIdx.x, wave = tid >> 6, lane = tid & 63;
  const int wm = (wave >> 1) * 64, wn = (wave & 1) * 32;
  const int cc = lane & 15, quad = lane >> 4;

  const unsigned short* abase =
      pws + ((size_t)((m0 + wm) >> 4) * 12) * 512 + lane * 8;
  const unsigned short* bbase =
      aos + (((size_t)b * 64 + ((n0 + wn) >> 4)) * 12) * 512 + lane * 8;

  f32x4 acc[4][2];
#pragma unroll
  for (int i = 0; i < 4; i++)
#pragma unroll
    for (int j = 0; j < 2; j++) acc[i][j] = (f32x4){0.f, 0.f, 0.f, 0.f};

  bf16x8 af[4], bfr[2];
#pragma unroll
  for (int t = 0; t < 4; t++) af[t] = *(const bf16x8*)(abase + (size_t)(t * 12) * 512);
#pragma unroll
  for (int t = 0; t < 2; t++) bfr[t] = *(const bf16x8*)(bbase + (size_t)(t * 12) * 512);

#pragma unroll 2
  for (int kc = 0; kc < 12; kc++) {
    const int k2 = (kc + 1 < 12) ? kc + 1 : 0;
    bf16x8 naf[4], nbf[2];
#pragma unroll
    for (int t = 0; t < 4; t++)
      naf[t] = *(const bf16x8*)(abase + (size_t)(t * 12 + k2) * 512);
#pragma unroll
    for (int t = 0; t < 2; t++)
      nbf[t] = *(const bf16x8*)(bbase + (size_t)(t * 12 + k2) * 512);
#pragma unroll
    for (int i = 0; i < 4; i++)
#pragma unroll
      for (int j = 0; j < 2; j++)
        acc[i][j] = __builtin_amdgcn_mfma_f32_16x16x32_bf16(af[i], bfr[j], acc[i][j], 0, 0, 0);
#pragma unroll
    for (int t = 0; t < 4; t++) af[t] = naf[t];
#pragma unroll
    for (int t = 0; t < 2; t++) bfr[t] = nbf[t];
  }

#pragma unroll
  for (int mt = 0; mt < 4; mt++) {
    const int cbase = m0 + wm + mt * 16 + quad * 4;
    const float4 bi4 = *(const float4*)(bias + cbase);
#pragma unroll
    for (int nt = 0; nt < 2; nt++) {
      const int n = n0 + wn + nt * 16 + cc;
      float* op = out + ((size_t)b * CH + cbase) * NPIX + n;
      op[0 * NPIX] = acc[mt][nt][0] + bi4.x;
      op[1 * NPIX] = acc[mt][nt][1] + bi4.y;
      op[2 * NPIX] = acc[mt][nt][2] + bi4.z;
      op[3 * NPIX] = acc[mt][nt][3] + bi4.w;
    }
  }
}

extern "C" void kernel_launch(void* const* d_in, const int* in_sizes, int n_in,
                              void* d_out, int out_size, void* d_ws, size_t ws_size,
                              hipStream_t stream) {
  const float* x      = (const float*)d_in[0];  // [16,384,32,32]
  const float* qkv_w  = (const float*)d_in[1];  // [1152,384]
  const float* proj_w = (const float*)d_in[2];  // [384,384]
  const float* proj_b = (const float*)d_in[3];  // [384]

  constexpr size_t SEG = (size_t)NB * NPIX * CH;  // 6291456
  unsigned short* ws  = (unsigned short*)d_ws;
  unsigned short* xtw = ws;                         // swizzled
  unsigned short* qbw = ws + SEG;
  unsigned short* kbw = ws + 2 * SEG;
  unsigned short* vtw = ws + 3 * SEG;
  unsigned short* aow = ws + 4 * SEG;               // swizzled
  unsigned short* wqw = ws + 5 * SEG;               // swizzled, 442368
  unsigned short* pww = wqw + (size_t)3 * CH * CH;  // swizzled, 147456

  prep_fused<<<2112, 256, 0, stream>>>(x, qkv_w, proj_w, xtw, wqw, pww);
  // grid x = b*8+ntile: XCD = x%8 pins each xt slice; y = 9 m-tiles
  qkv_mfma<<<dim3(NB * (NPIX / 128), (3 * CH) / 128), 256, 0, stream>>>(xtw, wqw, qbw, kbw, vtw);
  // grid (bh, qtile-of-128): same-bh blocks share an XCD; wave pairs split keys
  attn_mfma<<<dim3(NB * NHEAD, NPIX / 128), 256, 0, stream>>>(qbw, kbw, vtw, aow);
  proj_mfma<<<dim3(NB * (NPIX / 64), CH / 128), 256, 0, stream>>>(aow, pww, proj_b, (float*)d_out);
}

// Round 13
// 178.011 us; speedup vs baseline: 2.9528x; 2.9528x over previous
//
#include <hip/hip_runtime.h>

// Problem constants (fixed by the reference)
constexpr int CH    = 384;    // channels
constexpr int NPIX  = 1024;   // H*W = 32*32
constexpr int NHEAD = 12;
constexpr int DH    = 32;     // head dim
constexpr int NB    = 16;     // batch
constexpr float SCALE = 0.17677669529663689f;  // 32^-0.5
constexpr float LOG2E = 1.4426950408889634f;

typedef __attribute__((ext_vector_type(8))) short bf16x8;  // 8 bf16 (4 VGPRs)
typedef __attribute__((ext_vector_type(4))) float f32x4;   // MFMA C/D frag

// Fragment-major ("swizzled") operand layout for the LDS-free GEMMs:
// a K-major matrix [R][384] is stored as [R/16][12] blocks of 512 bf16;
// lane (quad*16+cc) holds row cc, k = quad*8..+7 of the 32-wide k-chunk, at
// offset lane*8.  Fragment load = base + lane*8 -> 1 KB coalesced per wave.
// elem (r, ch): off = ((r>>4)*12 + (ch>>5))*512 + (((ch>>3)&3)*16 + (r&15))*8 + (ch&7)

// pack two fp32 -> two bf16, round-half-up (3 VALU)
__device__ __forceinline__ unsigned pk2(float a, float b) {
  return __builtin_amdgcn_perm(__float_as_uint(b) + 0x8000u,
                               __float_as_uint(a) + 0x8000u, 0x07060302u);
}
// pack two fp32 -> two bf16, TRUNCATE (1 VALU) — P only; bias cancels in P/l.
__device__ __forceinline__ unsigned pk2t(float a, float b) {
  return __builtin_amdgcn_perm(__float_as_uint(b), __float_as_uint(a), 0x07060302u);
}

// 2^x on the VALU (v_exp_f32 computes 2^x natively)
#if __has_builtin(__builtin_amdgcn_exp2f)
#define EXP2F(x) __builtin_amdgcn_exp2f(x)
#else
#define EXP2F(x) exp2f(x)
#endif

// ---------------------------------------------------------------------------
// Fused prep: blocks [0,1536) transpose x [b][c][n] fp32 -> xt swizzled bf16;
// blocks [1536,2112) convert weights to swizzled bf16 (Q rows pre-scaled by
// SCALE*log2e: base-2 logits).
// ---------------------------------------------------------------------------
__global__ __launch_bounds__(256) void prep_fused(
    const float* __restrict__ x, const float* __restrict__ qw,
    const float* __restrict__ pw, unsigned short* __restrict__ xts,
    unsigned short* __restrict__ wqs, unsigned short* __restrict__ pws) {
  const int bx = blockIdx.x;
  const int tid = threadIdx.x;
  if (bx < 1536) {
    __shared__ float T[64][65];
    const int b = bx / 96, rem = bx - b * 96;
    const int c0 = (rem >> 4) * 64, n0 = (rem & 15) * 64;
    const float* xb = x + ((size_t)b * CH + c0) * NPIX + n0;
    const int rn = (tid & 15) * 4, rc = tid >> 4;
#pragma unroll
    for (int i = 0; i < 4; i++) {
      float4 v = *(const float4*)(xb + (size_t)(rc + i * 16) * NPIX + rn);
      T[rc + i * 16][rn + 0] = v.x;
      T[rc + i * 16][rn + 1] = v.y;
      T[rc + i * 16][rn + 2] = v.z;
      T[rc + i * 16][rn + 3] = v.w;
    }
    __syncthreads();
    const int wc = (tid & 15) * 4;  // channel offset within the 64-wide c tile
    const int ch = c0 + wc;         // 4 consecutive channels
    const int kc = ch >> 5, qd = (ch >> 3) & 3, j = ch & 7;
#pragma unroll
    for (int i = 0; i < 4; i++) {
      const int nl = (tid >> 4) + i * 16;       // local pixel row
      const int ng = n0 + nl;
      uint2 p = {pk2(T[wc][nl], T[wc + 1][nl]), pk2(T[wc + 2][nl], T[wc + 3][nl])};
      size_t off = (((size_t)b * 64 + (ng >> 4)) * 12 + kc) * 512 +
                   (qd * 16 + (ng & 15)) * 8 + j;
      *(uint2*)(xts + off) = p;
    }
  } else {
    const int idx = (bx - 1536) * 256 + tid;
    if (idx < 110592) {
      float4 v = ((const float4*)qw)[idx];
      const int o  = (idx * 4) / CH;  // 4 | 384: never crosses a row
      const int ch = (idx * 4) - o * CH;
      const float sc = (o < CH) ? SCALE * LOG2E : 1.0f;
      size_t off = (((size_t)(o >> 4)) * 12 + (ch >> 5)) * 512 +
                   (((ch >> 3) & 3) * 16 + (o & 15)) * 8 + (ch & 7);
      *(uint2*)(wqs + off) =
          (uint2){pk2(v.x * sc, v.y * sc), pk2(v.z * sc, v.w * sc)};
    } else {
      const int jdx = idx - 110592;
      float4 v = ((const float4*)pw)[jdx];
      const int o  = (jdx * 4) / CH;
      const int ch = (jdx * 4) - o * CH;
      size_t off = (((size_t)(o >> 4)) * 12 + (ch >> 5)) * 512 +
                   (((ch >> 3) & 3) * 16 + (o & 15)) * 8 + (ch & 7);
      *(uint2*)(pws + off) = (uint2){pk2(v.x, v.y), pk2(v.z, v.w)};
    }
  }
}

// ---------------------------------------------------------------------------
// QKV GEMM (R11 swizzled LDS-free, launch_bounds(256,3) — the proven config).
// ---------------------------------------------------------------------------
__global__ __launch_bounds__(256, 3) void qkv_mfma(
    const unsigned short* __restrict__ xts, const unsigned short* __restrict__ wqs,
    unsigned short* __restrict__ qb, unsigned short* __restrict__ kb,
    unsigned short* __restrict__ vtb) {
  const int bx = blockIdx.x;          // b = bx>>3, ntile = bx&7
  const int b  = bx >> 3;
  const int n0 = (bx & 7) * 128;
  const int m0 = blockIdx.y * 128;    // 0..8
  const int qkv_t = blockIdx.y / 3;   // 0=Q, 1=K, 2=V
  const int tid = threadIdx.x, wave = tid >> 6, lane = tid & 63;
  const int wm = (wave >> 1) * 64, wn = (wave & 1) * 64;
  const int cc = lane & 15, quad = lane >> 4;

  const unsigned short* abase =
      wqs + ((size_t)((m0 + wm) >> 4) * 12) * 512 + lane * 8;
  const unsigned short* bbase =
      xts + (((size_t)b * 64 + ((n0 + wn) >> 4)) * 12) * 512 + lane * 8;

  f32x4 acc[4][4];
#pragma unroll
  for (int i = 0; i < 4; i++)
#pragma unroll
    for (int j = 0; j < 4; j++) acc[i][j] = (f32x4){0.f, 0.f, 0.f, 0.f};

  bf16x8 af[4], bfr[4];
#pragma unroll
  for (int t = 0; t < 4; t++) af[t] = *(const bf16x8*)(abase + (size_t)(t * 12) * 512);
#pragma unroll
  for (int t = 0; t < 4; t++) bfr[t] = *(const bf16x8*)(bbase + (size_t)(t * 12) * 512);

#pragma unroll 2
  for (int kc = 0; kc < 12; kc++) {
    const int k2 = (kc + 1 < 12) ? kc + 1 : 0;  // wrap: redundant, in-bounds
    bf16x8 naf[4], nbf[4];
#pragma unroll
    for (int t = 0; t < 4; t++)
      naf[t] = *(const bf16x8*)(abase + (size_t)(t * 12 + k2) * 512);
#pragma unroll
    for (int t = 0; t < 4; t++)
      nbf[t] = *(const bf16x8*)(bbase + (size_t)(t * 12 + k2) * 512);

    if (qkv_t < 2) {
#pragma unroll
      for (int i = 0; i < 4; i++)
#pragma unroll
        for (int j = 0; j < 4; j++)
          acc[i][j] = __builtin_amdgcn_mfma_f32_16x16x32_bf16(af[i], bfr[j], acc[i][j], 0, 0, 0);
    } else {  // V: swap -> C rows = pixels, cols = weight-o
#pragma unroll
      for (int i = 0; i < 4; i++)
#pragma unroll
        for (int j = 0; j < 4; j++)
          acc[i][j] = __builtin_amdgcn_mfma_f32_16x16x32_bf16(bfr[i], af[j], acc[i][j], 0, 0, 0);
    }
#pragma unroll
    for (int t = 0; t < 4; t++) { af[t] = naf[t]; bfr[t] = nbf[t]; }
  }

  const int obase = m0 - qkv_t * CH;  // 0/128/256 within the Q/K/V segment
  if (qkv_t < 2) {
    unsigned short* dst0 = (qkv_t == 0) ? qb : kb;
#pragma unroll
    for (int mt = 0; mt < 4; mt++) {
      const int o = obase + wm + mt * 16 + quad * 4;  // [0,384)
      const int h = o >> 5, d0 = o & 31;
      unsigned short* drow = dst0 + ((size_t)(b * NHEAD + h) * NPIX) * DH + d0;
#pragma unroll
      for (int nt = 0; nt < 4; nt++) {
        const int n = n0 + wn + nt * 16 + cc;
        uint2 p = {pk2(acc[mt][nt][0], acc[mt][nt][1]),
                   pk2(acc[mt][nt][2], acc[mt][nt][3])};
        *(uint2*)(drow + (size_t)n * DH) = p;
      }
    }
  } else {
#pragma unroll
    for (int i = 0; i < 4; i++) {
      const int nbase = n0 + wn + i * 16 + quad * 4;
#pragma unroll
      for (int j = 0; j < 4; j++) {
        const int od = obase + wm + j * 16 + cc;
        const int h = od >> 5, dd = od & 31;
        unsigned short* vrow = vtb + ((size_t)(b * NHEAD + h) * DH + dd) * NPIX;
        *(uint2*)(vrow + nbase) = (uint2){pk2(acc[i][j][0], acc[i][j][1]),
                                          pk2(acc[i][j][2], acc[i][j][3])};
      }
    }
  }
}

// ---------------------------------------------------------------------------
// MFMA attention v12 = R12 structure with the spill FIXED: launch_bounds
// (256,4) gives the allocator 128 VGPRs (state needs ~90-110; R12's bound of
// 6 waves capped it at 85 -> accumulators spilled to scratch, 1.4 GB/dispatch
// of HBM traffic, 5x slowdown).  Split-K wave pairs: block = 2 q-subtiles x
// 2 key-halves, each wave 64 queries x 512 keys; exact unnormalized combine
// through reused Pbuf.  Grid (192, 8) = 1536 blocks, 4 blocks/CU resident.
// VALU-diet loop (matrix-pipe denominator, truncate-pack, skewed pipeline,
// base-2 softmax); XCD-pinned; output in proj's fragment-major layout.
// ---------------------------------------------------------------------------
__global__ __launch_bounds__(256, 4) void attn_mfma(
    const unsigned short* __restrict__ qb, const unsigned short* __restrict__ kb,
    const unsigned short* __restrict__ vtb, unsigned short* __restrict__ ao) {
  constexpr int PSTR = 36;  // 72 B rows: 18c mod 32 hits all 16 even residues
  // 18432 B; doubles as the split-K combine buffer (1152 float4)
  __shared__ __align__(16) unsigned short Pbuf[4][4][16][PSTR];

  const int bh   = blockIdx.x;  // 0..191  (x-major -> XCD = bh % 8)
  const int b    = bh / NHEAD;
  const int h    = bh - b * NHEAD;
  const int tid  = threadIdx.x;
  const int wave = tid >> 6;
  const int half = wave & 1;    // key half
  const int pairq = wave >> 1;  // q-subtile within block
  const int lane = tid & 63;
  const int c    = lane & 15;
  const int Q0   = lane >> 4;
  const int q0   = blockIdx.y * 128 + pairq * 64;

  bf16x8 Bq[4];
#pragma unroll
  for (int g = 0; g < 4; g++)
    Bq[g] = *(const bf16x8*)(qb + ((size_t)bh * NPIX + q0 + 16 * g + c) * DH + Q0 * 8);

  const unsigned short* kh  = kb + ((size_t)bh * NPIX + half * 512) * DH;
  const unsigned short* v0h = vtb + ((size_t)bh * DH + c) * NPIX + half * 512;
  const unsigned short* v1h = vtb + ((size_t)bh * DH + c + 16) * NPIX + half * 512;

  const f32x4 zero = {0.f, 0.f, 0.f, 0.f};
  const bf16x8 zero8 = {0, 0, 0, 0, 0, 0, 0, 0};
  const short ONE = (short)0x3F80;  // bf16 1.0
  const bf16x8 ones = {ONE, ONE, ONE, ONE, ONE, ONE, ONE, ONE};

  f32x4 o0[4], o1[4], ls[4];
#pragma unroll
  for (int g = 0; g < 4; g++) { o0[g] = zero; o1[g] = zero; ls[g] = zero; }

  unsigned short* prow[4];
#pragma unroll
  for (int g = 0; g < 4; g++) prow[g] = &Pbuf[wave][g][c][0];

  bf16x8 Ka0 = *(const bf16x8*)(kh + (size_t)c * DH + Q0 * 8);  // K(0)
  bf16x8 Ka1 = *(const bf16x8*)(kh + (size_t)(16 + c) * DH + Q0 * 8);
  bf16x8 Vr0 = zero8, Vr1 = zero8;              // V(t-1); PV(-1) adds 0
  bf16x8 Bp[4] = {zero8, zero8, zero8, zero8};  // P(t-1)

#pragma unroll 2
  for (int kt = 0; kt < 512; kt += 32) {
    const int kt2 = (kt + 32) & 511;  // wrap on last iter (redundant, in-bounds)
    bf16x8 nKa0 = *(const bf16x8*)(kh + (size_t)(kt2 + c) * DH + Q0 * 8);
    bf16x8 nKa1 = *(const bf16x8*)(kh + (size_t)(kt2 + 16 + c) * DH + Q0 * 8);
    bf16x8 nVa0 = *(const bf16x8*)(v0h + kt + Q0 * 8);
    bf16x8 nVa1 = *(const bf16x8*)(v1h + kt + Q0 * 8);

    // S(t) = K(t) . Q^T  (8 MFMA)
    f32x4 s0[4], s1[4];
#pragma unroll
    for (int g = 0; g < 4; g++) {
      s0[g] = __builtin_amdgcn_mfma_f32_16x16x32_bf16(Ka0, Bq[g], zero, 0, 0, 0);
      s1[g] = __builtin_amdgcn_mfma_f32_16x16x32_bf16(Ka1, Bq[g], zero, 0, 0, 0);
    }

    // PV(t-1) + denominator(t-1): 12 MFMA, all operands in registers
#pragma unroll
    for (int g = 0; g < 4; g++) {
      o0[g] = __builtin_amdgcn_mfma_f32_16x16x32_bf16(Vr0, Bp[g], o0[g], 0, 0, 0);
      o1[g] = __builtin_amdgcn_mfma_f32_16x16x32_bf16(Vr1, Bp[g], o1[g], 0, 0, 0);
      ls[g] = __builtin_amdgcn_mfma_f32_16x16x32_bf16(ones, Bp[g], ls[g], 0, 0, 0);
    }

    // p = 2^s, truncate-pack, LDS round-trip for P(t)
#pragma unroll
    for (int g = 0; g < 4; g++) {
      float p0[4], p1[4];
#pragma unroll
      for (int r = 0; r < 4; r++) p0[r] = EXP2F(s0[g][r]);
#pragma unroll
      for (int r = 0; r < 4; r++) p1[r] = EXP2F(s1[g][r]);
      *(uint2*)(prow[g] + 4 * Q0)      = (uint2){pk2t(p0[0], p0[1]), pk2t(p0[2], p0[3])};
      *(uint2*)(prow[g] + 16 + 4 * Q0) = (uint2){pk2t(p1[0], p1[1]), pk2t(p1[2], p1[3])};
    }
#pragma unroll
    for (int g = 0; g < 4; g++) Bp[g] = *(const bf16x8*)(prow[g] + 8 * Q0);

    Ka0 = nKa0; Ka1 = nKa1; Vr0 = nVa0; Vr1 = nVa1;
  }

  // drain: PV(last) + denominator(last)
#pragma unroll
  for (int g = 0; g < 4; g++) {
    o0[g] = __builtin_amdgcn_mfma_f32_16x16x32_bf16(Vr0, Bp[g], o0[g], 0, 0, 0);
    o1[g] = __builtin_amdgcn_mfma_f32_16x16x32_bf16(Vr1, Bp[g], o1[g], 0, 0, 0);
    ls[g] = __builtin_amdgcn_mfma_f32_16x16x32_bf16(ones, Bp[g], ls[g], 0, 0, 0);
  }

  // ---- split-K combine (exact: unnormalized partials add) ----
  float4* cb = (float4*)&Pbuf[0][0][0][0];   // 1152 float4
  float4* ob = cb + (size_t)pairq * 8 * 64;  // 8 slots per q-subtile
  __syncthreads();                           // all Pbuf P-reads done
  if (half) {
#pragma unroll
    for (int g = 0; g < 4; g++) {
      ob[(g * 2 + 0) * 64 + lane] = (float4){o0[g][0], o0[g][1], o0[g][2], o0[g][3]};
      ob[(g * 2 + 1) * 64 + lane] = (float4){o1[g][0], o1[g][1], o1[g][2], o1[g][3]};
    }
    cb[1024 + pairq * 64 + lane] = (float4){ls[0][0], ls[1][0], ls[2][0], ls[3][0]};
  }
  __syncthreads();
  if (!half) {
    const float4 lo = cb[1024 + pairq * 64 + lane];
    const float lt[4] = {ls[0][0] + lo.x, ls[1][0] + lo.y,
                         ls[2][0] + lo.z, ls[3][0] + lo.w};
#pragma unroll
    for (int g = 0; g < 4; g++) {
      const float4 a0 = ob[(g * 2 + 0) * 64 + lane];
      const float4 a1 = ob[(g * 2 + 1) * 64 + lane];
      const float inv = 1.0f / lt[g];
      // proj fragment-major store: row-block (q0>>4)+g, k-chunk h, row c
      unsigned short* op = ao +
          (((size_t)b * 64 + (q0 >> 4) + g) * 12 + h) * 512 + c * 8 + 4 * (Q0 & 1);
      *(uint2*)(op + (Q0 >> 1) * 128) =
          (uint2){pk2((o0[g][0] + a0.x) * inv, (o0[g][1] + a0.y) * inv),
                  pk2((o0[g][2] + a0.z) * inv, (o0[g][3] + a0.w) * inv)};
      *(uint2*)(op + (2 + (Q0 >> 1)) * 128) =
          (uint2){pk2((o1[g][0] + a1.x) * inv, (o1[g][1] + a1.y) * inv),
                  pk2((o1[g][2] + a1.z) * inv, (o1[g][3] + a1.w) * inv)};
    }
  }
}

// ---------------------------------------------------------------------------
// Output projection v4: LDS-free swizzled, 128m x 64n tiles.
// Grid (256, 3) = 768 blocks = 3/CU (vs 384 = 1.5/CU: half the CUs idled).
// launch_bounds(256,3): VGPR-safe (state ~60).
// ---------------------------------------------------------------------------
__global__ __launch_bounds__(256, 3) void proj_mfma(
    const unsigned short* __restrict__ aos, const unsigned short* __restrict__ pws,
    const float* __restrict__ bias, float* __restrict__ out) {
  const int bx = blockIdx.x;          // 0..255: b = bx>>4, ntile = bx&15
  const int b  = bx >> 4;
  const int n0 = (bx & 15) * 64;
  const int m0 = blockIdx.y * 128;
  const int tid = threadIdx.x, wave = tid >> 6, lane = tid & 63;
  const int wm = (wave >> 1) * 64, wn = (wave & 1) * 32;
  const int cc = lane & 15, quad = lane >> 4;

  const unsigned short* abase =
      pws + ((size_t)((m0 + wm) >> 4) * 12) * 512 + lane * 8;
  const unsigned short* bbase =
      aos + (((size_t)b * 64 + ((n0 + wn) >> 4)) * 12) * 512 + lane * 8;

  f32x4 acc[4][2];
#pragma unroll
  for (int i = 0; i < 4; i++)
#pragma unroll
    for (int j = 0; j < 2; j++) acc[i][j] = (f32x4){0.f, 0.f, 0.f, 0.f};

  bf16x8 af[4], bfr[2];
#pragma unroll
  for (int t = 0; t < 4; t++) af[t] = *(const bf16x8*)(abase + (size_t)(t * 12) * 512);
#pragma unroll
  for (int t = 0; t < 2; t++) bfr[t] = *(const bf16x8*)(bbase + (size_t)(t * 12) * 512);

#pragma unroll 2
  for (int kc = 0; kc < 12; kc++) {
    const int k2 = (kc + 1 < 12) ? kc + 1 : 0;
    bf16x8 naf[4], nbf[2];
#pragma unroll
    for (int t = 0; t < 4; t++)
      naf[t] = *(const bf16x8*)(abase + (size_t)(t * 12 + k2) * 512);
#pragma unroll
    for (int t = 0; t < 2; t++)
      nbf[t] = *(const bf16x8*)(bbase + (size_t)(t * 12 + k2) * 512);
#pragma unroll
    for (int i = 0; i < 4; i++)
#pragma unroll
      for (int j = 0; j < 2; j++)
        acc[i][j] = __builtin_amdgcn_mfma_f32_16x16x32_bf16(af[i], bfr[j], acc[i][j], 0, 0, 0);
#pragma unroll
    for (int t = 0; t < 4; t++) af[t] = naf[t];
#pragma unroll
    for (int t = 0; t < 2; t++) bfr[t] = nbf[t];
  }

#pragma unroll
  for (int mt = 0; mt < 4; mt++) {
    const int cbase = m0 + wm + mt * 16 + quad * 4;
    const float4 bi4 = *(const float4*)(bias + cbase);
#pragma unroll
    for (int nt = 0; nt < 2; nt++) {
      const int n = n0 + wn + nt * 16 + cc;
      float* op = out + ((size_t)b * CH + cbase) * NPIX + n;
      op[0 * NPIX] = acc[mt][nt][0] + bi4.x;
      op[1 * NPIX] = acc[mt][nt][1] + bi4.y;
      op[2 * NPIX] = acc[mt][nt][2] + bi4.z;
      op[3 * NPIX] = acc[mt][nt][3] + bi4.w;
    }
  }
}

extern "C" void kernel_launch(void* const* d_in, const int* in_sizes, int n_in,
                              void* d_out, int out_size, void* d_ws, size_t ws_size,
                              hipStream_t stream) {
  const float* x      = (const float*)d_in[0];  // [16,384,32,32]
  const float* qkv_w  = (const float*)d_in[1];  // [1152,384]
  const float* proj_w = (const float*)d_in[2];  // [384,384]
  const float* proj_b = (const float*)d_in[3];  // [384]

  constexpr size_t SEG = (size_t)NB * NPIX * CH;  // 6291456
  unsigned short* ws  = (unsigned short*)d_ws;
  unsigned short* xtw = ws;                         // swizzled
  unsigned short* qbw = ws + SEG;
  unsigned short* kbw = ws + 2 * SEG;
  unsigned short* vtw = ws + 3 * SEG;
  unsigned short* aow = ws + 4 * SEG;               // swizzled
  unsigned short* wqw = ws + 5 * SEG;               // swizzled, 442368
  unsigned short* pww = wqw + (size_t)3 * CH * CH;  // swizzled, 147456

  prep_fused<<<2112, 256, 0, stream>>>(x, qkv_w, proj_w, xtw, wqw, pww);
  // grid x = b*8+ntile: XCD = x%8 pins each xt slice; y = 9 m-tiles
  qkv_mfma<<<dim3(NB * (NPIX / 128), (3 * CH) / 128), 256, 0, stream>>>(xtw, wqw, qbw, kbw, vtw);
  // grid (bh, qtile-of-128): same-bh blocks share an XCD; wave pairs split keys
  attn_mfma<<<dim3(NB * NHEAD, NPIX / 128), 256, 0, stream>>>(qbw, kbw, vtw, aow);
  proj_mfma<<<dim3(NB * (NPIX / 64), CH / 128), 256, 0, stream>>>(aow, pww, proj_b, (float*)d_out);
}